// Round 4
// baseline (130.161 us; speedup 1.0000x reference)
//
#include <hip/hip_runtime.h>

#define B_   16
#define NK_  256
#define NQ_  256
#define DK_  256
#define H_   128
#define DV_  256

// 2*log2(e): features prescaled so exp2(C2X*x) = e^{2x}
#define C2X 2.8853900817779268f
// log2(e) for softmax exp
#define L2E 1.4426950408889634f
#define MASKV -1.0e5f

typedef float f4 __attribute__((ext_vector_type(4)));

__device__ __forceinline__ float exp2_fast(float x) { return __builtin_amdgcn_exp2f(x); }
__device__ __forceinline__ float rcp_fast(float x)  { return __builtin_amdgcn_rcpf(x); }

// ---------------------------------------------------------------------------
// Kernel A: projections -> EXponentiated features.
//   blocks 0..127   : kfE[b][k][h]        = exp2(C2X * (key  @ Wk))
//   blocks 128..255 : qE4[b][h/4][q][4]   = exp2(C2X * (query @ Wq))  (h4-interleaved)
// Block = 32 flat rows x 128 cols; thread = 4x4 register micro-tile.
// ~93% fma density; est ~4.5us vs 3.4us VALU floor.
// ---------------------------------------------------------------------------
__global__ __launch_bounds__(256) void proj_kernel(
    const float* __restrict__ key, const float* __restrict__ query,
    const float* __restrict__ Wk,  const float* __restrict__ Wq,
    float* __restrict__ kfE, float* __restrict__ qE4)
{
    __shared__ alignas(16) float A_s[32 * 256];   // 32 KB
    __shared__ alignas(16) float W_s[64 * 128];   // 32 KB

    const int blk = blockIdx.x;
    const int tid = threadIdx.x;
    const bool isQ = blk >= 128;
    const int rb = (blk & 127) * 32;              // flat row base (b*256 + row)

    const float* __restrict__ A = isQ ? query : key;
    const float* __restrict__ W = isQ ? Wq : Wk;

    {
        const f4* src = (const f4*)(A + (size_t)rb * DK_);
        f4* dst = (f4*)A_s;
#pragma unroll
        for (int j = 0; j < 8; ++j) dst[tid + 256 * j] = src[tid + 256 * j];
    }

    const int rg = (tid >> 5) * 4;                // row group: 4 rows
    const int c4 = (tid & 31) * 4;                // col base:  4 cols

    f4 acc[4];
#pragma unroll
    for (int r = 0; r < 4; ++r) acc[r] = (f4){0.f, 0.f, 0.f, 0.f};

    for (int kc = 0; kc < DK_; kc += 64) {
        __syncthreads();
        {
            const f4* wsrc = (const f4*)(W + (size_t)kc * H_);
            f4* wdst = (f4*)W_s;
#pragma unroll
            for (int j = 0; j < 8; ++j) wdst[tid + 256 * j] = wsrc[tid + 256 * j];
        }
        __syncthreads();
#pragma unroll 2
        for (int k = 0; k < 64; k += 4) {
            f4 w0 = *(const f4*)(W_s + (k + 0) * H_ + c4);
            f4 w1 = *(const f4*)(W_s + (k + 1) * H_ + c4);
            f4 w2 = *(const f4*)(W_s + (k + 2) * H_ + c4);
            f4 w3 = *(const f4*)(W_s + (k + 3) * H_ + c4);
#pragma unroll
            for (int r = 0; r < 4; ++r) {
                f4 a = *(const f4*)(A_s + (rg + r) * 256 + kc + k);
                acc[r] += a[0] * w0;
                acc[r] += a[1] * w1;
                acc[r] += a[2] * w2;
                acc[r] += a[3] * w3;
            }
        }
    }

    if (!isQ) {
        float* dst = kfE + (size_t)(rb + rg) * H_ + c4;
#pragma unroll
        for (int r = 0; r < 4; ++r) {
            f4 o;
#pragma unroll
            for (int cc = 0; cc < 4; ++cc) o[cc] = exp2_fast(C2X * acc[r][cc]);
            *(f4*)(dst + (size_t)r * H_) = o;
        }
    } else {
        const int b  = rb >> 8;
        const int q0 = (rb & 255) + rg;
        f4* dst = (f4*)qE4 + ((size_t)(b * 32 + (c4 >> 2))) * NQ_ + q0;
#pragma unroll
        for (int r = 0; r < 4; ++r) {
            f4 o;
#pragma unroll
            for (int cc = 0; cc < 4; ++cc) o[cc] = exp2_fast(C2X * acc[r][cc]);
            dst[r] = o;
        }
    }
}

// ---------------------------------------------------------------------------
// Kernel B: fused scores + masked softmax + PV.  512 blocks x 256 threads,
// 8 k-rows per block (b and k-tile rotated across dispatch rounds).
// Phase 1: wave = q-CHUNK (rotated per block so masked chunks spread across
//          SIMDs); eq held in registers, reused across all 8 k-rows ->
//          qE4 global traffic /8 vs round-3; genuinely trans-pipe-bound.
// Phase 2: softmax per k-row (2 rows/wave), attn written back into sc_s.
// Phase 3: wave rq takes q = rq (mod 4); thread carries 8 k-accumulators so
//          value is read ONCE per block; LDS ds_add_f32 reduce (8 KB).
// LDS 21 KB, VGPR ~110 -> ~4 waves/SIMD.
// ---------------------------------------------------------------------------
__global__ __launch_bounds__(256) void attn_kernel(
    const float* __restrict__ kfE, const float* __restrict__ qE4,
    const float* __restrict__ value, const int* __restrict__ vlens,
    const float* __restrict__ wv, float* __restrict__ out)
{
    __shared__ alignas(16) float sc_s[8 * 260];    // scores/attn [k][q]
    __shared__ alignas(16) float kf_s[8 * 132];    // Ek rows (pad 132)
    __shared__ alignas(16) float wv2_s[128];       // 2*wv
    __shared__ alignas(16) float red_s[8 * 256];   // PV reduction [k][d]

    const int x    = blockIdx.x;
    const int qu   = x >> 7;                       // round 0..3
    const int xi   = x & 127;
    const int b    = (xi + (qu << 2)) & 15;
    const int kt   = (xi >> 4) + (qu << 3);        // 0..31
    const int k0   = kt << 3;
    const int rot  = ((xi >> 4) + qu) & 3;
    const int tid  = threadIdx.x;
    const int w    = tid >> 6;
    const int lane = tid & 63;
    const int valid  = vlens[b];
    const int nchunk = (valid + 63) >> 6;          // 1..4

    // stage Ek tile (8 x 128), 2*wv, zero red_s
    {
        const int k = tid >> 5, h4 = tid & 31;
        f4 v = ((const f4*)(kfE + ((size_t)(b * NK_ + k0 + k)) * H_))[h4];
        *(f4*)(kf_s + k * 132 + (h4 << 2)) = v;
    }
    if (tid < 32) {
        f4 wvv = ((const f4*)wv)[tid];
        ((f4*)wv2_s)[tid] = 2.f * wvv;
    }
    ((f4*)red_s)[tid]       = (f4){0.f, 0.f, 0.f, 0.f};
    ((f4*)red_s)[tid + 256] = (f4){0.f, 0.f, 0.f, 0.f};

    // sum(wv) from global (L1 broadcast), independent of staging
    float sumwv;
    {
        f4 sw = {0.f, 0.f, 0.f, 0.f};
#pragma unroll
        for (int i = 0; i < 32; ++i) sw += ((const f4*)wv)[i];
        sumwv = (sw[0] + sw[1]) + (sw[2] + sw[3]);
    }
    __syncthreads();

    // ---- Phase 1: this wave computes q-chunk c for ALL 8 k-rows.
    {
        const int c = (w + rot) & 3;
        if (c < nchunk) {
            const int q = (c << 6) + lane;
            const f4* eqp = (const f4*)qE4 + (size_t)b * (32 * NQ_) + q;

            float acc[8];
#pragma unroll
            for (int k = 0; k < 8; ++k) acc[k] = 0.f;

#pragma unroll
            for (int half = 0; half < 2; ++half) {
                f4 eq[16];
#pragma unroll
                for (int i = 0; i < 16; ++i)
                    eq[i] = eqp[(size_t)(half * 16 + i) * NQ_];
#pragma unroll
                for (int i = 0; i < 16; ++i) {
                    const int h4 = (half * 16 + i) << 2;
                    const f4 w4 = *(const f4*)(wv2_s + h4);
                    const f4 e  = eq[i];
#pragma unroll
                    for (int k = 0; k < 8; ++k) {
                        const f4 ek = *(const f4*)(kf_s + k * 132 + h4);
                        acc[k] = fmaf(w4[0], rcp_fast(fmaf(ek[0], e[0], 1.f)), acc[k]);
                        acc[k] = fmaf(w4[1], rcp_fast(fmaf(ek[1], e[1], 1.f)), acc[k]);
                        acc[k] = fmaf(w4[2], rcp_fast(fmaf(ek[2], e[2], 1.f)), acc[k]);
                        acc[k] = fmaf(w4[3], rcp_fast(fmaf(ek[3], e[3], 1.f)), acc[k]);
                    }
                }
            }
#pragma unroll
            for (int k = 0; k < 8; ++k)
                sc_s[k * 260 + q] = sumwv - acc[k];
        }
    }
    __syncthreads();

    // ---- Phase 2: masked softmax per k-row (wave handles rows 2w, 2w+1);
    // attn written back into sc_s in place.
    {
#pragma unroll
        for (int kk = 0; kk < 2; ++kk) {
            const int k = (w << 1) + kk;
            float* row = sc_s + k * 260;
            float s[4];
            float m = MASKV;
#pragma unroll
            for (int j = 0; j < 4; ++j) {
                const int q = (j << 6) + lane;
                s[j] = (q < valid) ? row[q] : MASKV;
                m = fmaxf(m, s[j]);
            }
#pragma unroll
            for (int off = 32; off >= 1; off >>= 1)
                m = fmaxf(m, __shfl_xor(m, off, 64));
            float ssum = 0.f;
#pragma unroll
            for (int j = 0; j < 4; ++j) {
                s[j] = exp2_fast(L2E * (s[j] - m));   // masked -> 0
                ssum += s[j];
            }
#pragma unroll
            for (int off = 32; off >= 1; off >>= 1)
                ssum += __shfl_xor(ssum, off, 64);
            const float inv = rcp_fast(ssum);
#pragma unroll
            for (int j = 0; j < 4; ++j)
                row[(j << 6) + lane] = s[j] * inv;
        }
    }
    __syncthreads();

    // ---- Phase 3: out[b][k0+k][d] = sum_q attn[k][q] * value[b][q][d]
    // wave rq = w takes q = w (mod 4); 8 k-accumulators per thread.
    {
        const int d4 = lane << 2;
        const float* vb = value + (size_t)b * (NQ_ * DV_) + d4;
        f4 o[8];
#pragma unroll
        for (int k = 0; k < 8; ++k) o[k] = (f4){0.f, 0.f, 0.f, 0.f};
#pragma unroll 2
        for (int q = w; q < valid; q += 4) {
            const f4 v = *(const f4*)(vb + (size_t)q * DV_);
#pragma unroll
            for (int k = 0; k < 8; ++k)
                o[k] += sc_s[k * 260 + q] * v;    // uniform LDS broadcast
        }
#pragma unroll
        for (int k = 0; k < 8; ++k) {
            float* p = red_s + (k << 8) + d4;
            atomicAdd(p + 0, o[k][0]);
            atomicAdd(p + 1, o[k][1]);
            atomicAdd(p + 2, o[k][2]);
            atomicAdd(p + 3, o[k][3]);
        }
    }
    __syncthreads();

    // store: 8 k x 256 d = 512 f4, 2 per thread
    {
#pragma unroll
        for (int e = 0; e < 2; ++e) {
            const int i  = tid + (e << 8);        // f4 index
            const int k  = i >> 6;
            const int dd = (i & 63) << 2;
            f4 ov = *(const f4*)(red_s + (k << 8) + dd);
            *(f4*)(out + ((size_t)(b * NK_ + k0 + k)) * DV_ + dd) = ov;
        }
    }
}

// ---------------------------------------------------------------------------
extern "C" void kernel_launch(void* const* d_in, const int* in_sizes, int n_in,
                              void* d_out, int out_size, void* d_ws, size_t ws_size,
                              hipStream_t stream)
{
    const float* key   = (const float*)d_in[0];
    const float* query = (const float*)d_in[1];
    const float* value = (const float*)d_in[2];
    const int*   vlens = (const int*)  d_in[3];
    const float* Wk    = (const float*)d_in[4];
    const float* Wq    = (const float*)d_in[5];
    const float* wv    = (const float*)d_in[6];
    float* outp = (float*)d_out;

    float* kfE = (float*)d_ws;                        // [B][NK][H]      2 MB
    float* qE4 = kfE + (size_t)B_ * NK_ * H_;         // [B][H/4][NQ][4] 2 MB

    hipLaunchKernelGGL(proj_kernel, dim3(256), dim3(256), 0, stream,
                       key, query, Wk, Wq, kfE, qE4);
    hipLaunchKernelGGL(attn_kernel, dim3(512), dim3(256), 0, stream,
                       kfE, qE4, value, vlens, wv, outp);
}

// Round 5
// 103.474 us; speedup vs baseline: 1.2579x; 1.2579x over previous
//
#include <hip/hip_runtime.h>

#define B_   16
#define NK_  256
#define NQ_  256
#define DK_  256
#define H_   128
#define DV_  256

// 2*log2(e): features prescaled so exp2(C2X*x) = e^{2x}
#define C2X 2.8853900817779268f
// log2(e) for softmax exp
#define L2E 1.4426950408889634f
#define MASKV -1.0e5f

typedef float f4 __attribute__((ext_vector_type(4)));

__device__ __forceinline__ float exp2_fast(float x) { return __builtin_amdgcn_exp2f(x); }
__device__ __forceinline__ float rcp_fast(float x)  { return __builtin_amdgcn_rcpf(x); }

// ---------------------------------------------------------------------------
// Kernel A: projections -> EXponentiated features.  (unchanged from R3)
//   blocks 0..127   : kfE[b][k][h]        = exp2(C2X * (key  @ Wk))
//   blocks 128..255 : qE4[b][h/4][q][4]   = exp2(C2X * (query @ Wq))
// ---------------------------------------------------------------------------
__global__ __launch_bounds__(256) void proj_kernel(
    const float* __restrict__ key, const float* __restrict__ query,
    const float* __restrict__ Wk,  const float* __restrict__ Wq,
    float* __restrict__ kfE, float* __restrict__ qE4)
{
    __shared__ alignas(16) float A_s[32 * 256];   // 32 KB
    __shared__ alignas(16) float W_s[64 * 128];   // 32 KB

    const int blk = blockIdx.x;
    const int tid = threadIdx.x;
    const bool isQ = blk >= 128;
    const int rb = (blk & 127) * 32;              // flat row base (b*256 + row)

    const float* __restrict__ A = isQ ? query : key;
    const float* __restrict__ W = isQ ? Wq : Wk;

    {
        const f4* src = (const f4*)(A + (size_t)rb * DK_);
        f4* dst = (f4*)A_s;
#pragma unroll
        for (int j = 0; j < 8; ++j) dst[tid + 256 * j] = src[tid + 256 * j];
    }

    const int rg = (tid >> 5) * 4;                // row group: 4 rows
    const int c4 = (tid & 31) * 4;                // col base:  4 cols

    f4 acc[4];
#pragma unroll
    for (int r = 0; r < 4; ++r) acc[r] = (f4){0.f, 0.f, 0.f, 0.f};

    for (int kc = 0; kc < DK_; kc += 64) {
        __syncthreads();
        {
            const f4* wsrc = (const f4*)(W + (size_t)kc * H_);
            f4* wdst = (f4*)W_s;
#pragma unroll
            for (int j = 0; j < 8; ++j) wdst[tid + 256 * j] = wsrc[tid + 256 * j];
        }
        __syncthreads();
#pragma unroll 2
        for (int k = 0; k < 64; k += 4) {
            f4 w0 = *(const f4*)(W_s + (k + 0) * H_ + c4);
            f4 w1 = *(const f4*)(W_s + (k + 1) * H_ + c4);
            f4 w2 = *(const f4*)(W_s + (k + 2) * H_ + c4);
            f4 w3 = *(const f4*)(W_s + (k + 3) * H_ + c4);
#pragma unroll
            for (int r = 0; r < 4; ++r) {
                f4 a = *(const f4*)(A_s + (rg + r) * 256 + kc + k);
                acc[r] += a[0] * w0;
                acc[r] += a[1] * w1;
                acc[r] += a[2] * w2;
                acc[r] += a[3] * w3;
            }
        }
    }

    if (!isQ) {
        float* dst = kfE + (size_t)(rb + rg) * H_ + c4;
#pragma unroll
        for (int r = 0; r < 4; ++r) {
            f4 o;
#pragma unroll
            for (int cc = 0; cc < 4; ++cc) o[cc] = exp2_fast(C2X * acc[r][cc]);
            *(f4*)(dst + (size_t)r * H_) = o;
        }
    } else {
        const int b  = rb >> 8;
        const int q0 = (rb & 255) + rg;
        f4* dst = (f4*)qE4 + ((size_t)(b * 32 + (c4 >> 2))) * NQ_ + q0;
#pragma unroll
        for (int r = 0; r < 4; ++r) {
            f4 o;
#pragma unroll
            for (int cc = 0; cc < 4; ++cc) o[cc] = exp2_fast(C2X * acc[r][cc]);
            dst[r] = o;
        }
    }
}

// ---------------------------------------------------------------------------
// Kernel B: fused scores + masked softmax + PV.  1024 blocks x 256 threads
// (R3 structure: 4 k-rows/block, wave = k-row, wave-uniform chunk loop ->
// all waves active, 4 waves/SIMD).  R5 changes:
//  - ek & wv read through readfirstlane-uniform pointers -> s_load_dwordx4
//    on the scalar pipe; NO LDS and no staging barrier in phase 1.
//  - factor 2 folded out of the inner loop (score = sumwv - 2*acc).
// Per term: v_fma(ek,eq,1) + v_rcp + v_fmac  -> trans-pipe-bound (~3.4us).
// ---------------------------------------------------------------------------
__global__ __launch_bounds__(256) void attn_kernel(
    const float* __restrict__ kfE, const float* __restrict__ qE4,
    const float* __restrict__ value, const int* __restrict__ vlens,
    const float* __restrict__ wv, float* __restrict__ out)
{
    __shared__ alignas(16) float at4_s[256 * 4];   // attn transposed [q][k]
    __shared__ alignas(16) float red_s[16 * 256];  // phase-3 partials

    const int x    = blockIdx.x;
    const int qu   = x >> 8;                       // dispatch round 0..3
    const int xi   = x & 255;
    const int b    = (xi + (qu << 2)) & 15;        // b rotated for balance
    const int kt   = (xi >> 4) + (qu << 4);        // 0..63
    const int k0   = kt << 2;
    const int tid  = threadIdx.x;
    const int lane = tid & 63;
    // force wave index into an SGPR so ek addresses are provably uniform
    const int wu   = __builtin_amdgcn_readfirstlane(tid >> 6);
    const int valid  = vlens[b];
    const int nchunk = (valid + 63) >> 6;          // 1..4

    // sum(wv): uniform addresses -> s_load; 4 independent chains
    float sumwv;
    {
        f4 sw = {0.f, 0.f, 0.f, 0.f};
#pragma unroll
        for (int i = 0; i < 32; ++i) sw += ((const f4*)wv)[i];
        sumwv = (sw[0] + sw[1]) + (sw[2] + sw[3]);
    }

    // ---- Phase 1: scores for k-row (k0+wu), q = 64j+lane, j < nchunk.
    float accA[4], accB[4];
#pragma unroll
    for (int j = 0; j < 4; ++j) { accA[j] = 0.f; accB[j] = 0.f; }

    {
        const float* ekp = kfE + ((size_t)(b * NK_ + k0 + wu)) * H_;  // uniform
        const f4*    eq0 = (const f4*)qE4 + (size_t)b * (32 * NQ_) + lane;

        auto run = [&](int NC) {
#pragma unroll 4
            for (int h4 = 0; h4 < 32; ++h4) {
                const f4 ek = *(const f4*)(ekp + (h4 << 2));   // s_load_dwordx4
                const f4 w4 = *(const f4*)(wv  + (h4 << 2));   // s_load_dwordx4
#pragma unroll
                for (int j = 0; j < 4; ++j) {
                    if (j >= NC) break;
                    const f4 eq = eq0[(size_t)h4 * NQ_ + (j << 6)];
                    accA[j] = fmaf(w4[0], rcp_fast(fmaf(ek[0], eq[0], 1.f)), accA[j]);
                    accB[j] = fmaf(w4[1], rcp_fast(fmaf(ek[1], eq[1], 1.f)), accB[j]);
                    accA[j] = fmaf(w4[2], rcp_fast(fmaf(ek[2], eq[2], 1.f)), accA[j]);
                    accB[j] = fmaf(w4[3], rcp_fast(fmaf(ek[3], eq[3], 1.f)), accB[j]);
                }
            }
        };
        switch (nchunk) {
            case 1: run(1); break;
            case 2: run(2); break;
            case 3: run(3); break;
            default: run(4); break;
        }
    }

    // ---- Phase 2: in-wave masked softmax over this k-row's 256 q.
    {
        float s[4];
#pragma unroll
        for (int j = 0; j < 4; ++j) {
            const int q = (j << 6) + lane;
            s[j] = (j < nchunk && q < valid)
                 ? (sumwv - 2.f * (accA[j] + accB[j])) : MASKV;
        }
        float m = fmaxf(fmaxf(s[0], s[1]), fmaxf(s[2], s[3]));
#pragma unroll
        for (int off = 32; off >= 1; off >>= 1)
            m = fmaxf(m, __shfl_xor(m, off, 64));
        float ssum = 0.f;
#pragma unroll
        for (int j = 0; j < 4; ++j) {
            s[j] = exp2_fast(L2E * (s[j] - m));   // masked -> 0
            ssum += s[j];
        }
#pragma unroll
        for (int off = 32; off >= 1; off >>= 1)
            ssum += __shfl_xor(ssum, off, 64);
        const float inv = rcp_fast(ssum);
#pragma unroll
        for (int j = 0; j < 4; ++j)
            at4_s[(((j << 6) + lane) << 2) + wu] = s[j] * inv;
    }
    __syncthreads();

    // ---- Phase 3: out[b][k0+k][d] = sum_q attn[q][k] * value[b][q][d]
    // wave rq takes q = rq (mod 4); thread holds all 4 k accumulators.
    {
        const int rq = tid >> 6;
        const int d4 = lane << 2;
        const float* vb = value + (size_t)b * (NQ_ * DV_) + d4;
        f4 o0 = {0.f,0.f,0.f,0.f}, o1 = o0, o2 = o0, o3 = o0;
#pragma unroll 4
        for (int q = rq; q < valid; q += 4) {
            f4 v  = *(const f4*)(vb + (size_t)q * DV_);
            f4 a4 = *(const f4*)(at4_s + (q << 2));   // uniform b128 broadcast
            o0 += a4[0] * v;
            o1 += a4[1] * v;
            o2 += a4[2] * v;
            o3 += a4[3] * v;
        }
        float* rs = red_s + (rq << 10) + d4;          // red_s[rq*4+k][256]
        *(f4*)(rs + 0)    = o0;
        *(f4*)(rs + 256)  = o1;
        *(f4*)(rs + 512)  = o2;
        *(f4*)(rs + 768)  = o3;
    }
    __syncthreads();

    // cross-wave reduce + store
    {
        const int k  = tid >> 6;
        const int d4 = lane << 2;
        const float* rs = red_s + (k << 8) + d4;
        f4 o = *(const f4*)(rs) + *(const f4*)(rs + 1024)
             + *(const f4*)(rs + 2048) + *(const f4*)(rs + 3072);
        *(f4*)(out + ((size_t)(b * NK_ + k0 + k)) * DV_ + d4) = o;
    }
}

// ---------------------------------------------------------------------------
extern "C" void kernel_launch(void* const* d_in, const int* in_sizes, int n_in,
                              void* d_out, int out_size, void* d_ws, size_t ws_size,
                              hipStream_t stream)
{
    const float* key   = (const float*)d_in[0];
    const float* query = (const float*)d_in[1];
    const float* value = (const float*)d_in[2];
    const int*   vlens = (const int*)  d_in[3];
    const float* Wk    = (const float*)d_in[4];
    const float* Wq    = (const float*)d_in[5];
    const float* wv    = (const float*)d_in[6];
    float* outp = (float*)d_out;

    float* kfE = (float*)d_ws;                        // [B][NK][H]      2 MB
    float* qE4 = kfE + (size_t)B_ * NK_ * H_;         // [B][H/4][NQ][4] 2 MB

    hipLaunchKernelGGL(proj_kernel, dim3(256), dim3(256), 0, stream,
                       key, query, Wk, Wq, kfE, qE4);
    hipLaunchKernelGGL(attn_kernel, dim3(1024), dim3(256), 0, stream,
                       kfE, qE4, value, vlens, wv, outp);
}